// Round 12
// baseline (306.222 us; speedup 1.0000x reference)
//
#include <hip/hip_runtime.h>
#include <hip/hip_bf16.h>

#define NN 10000
#define NE 100000
#define NSEG_MAX 16384   // >= sum_v ceil(degc/16) <= (E + 15N)/16 = 15625

typedef __bf16 bf16x8 __attribute__((ext_vector_type(8)));
typedef float  f32x4  __attribute__((ext_vector_type(4)));
typedef unsigned u32x4 __attribute__((ext_vector_type(4)));

__device__ __forceinline__ f32x4 relu4(f32x4 a) {
    a.x = fmaxf(a.x, 0.f); a.y = fmaxf(a.y, 0.f);
    a.z = fmaxf(a.z, 0.f); a.w = fmaxf(a.w, 0.f);
    return a;
}

__device__ __forceinline__ unsigned pk2(float a, float b) {
    unsigned ua = (unsigned)__builtin_bit_cast(unsigned short, (__bf16)a);
    unsigned ub = (unsigned)__builtin_bit_cast(unsigned short, (__bf16)b);
    return ua | (ub << 16);
}

// ---------------- one-time kernels ----------------
// Swizzle tables (all MFMA-frag layouts), h/coord init, row+col degree counts.
__global__ void k_setup(const float* __restrict__ w3, __bf16* __restrict__ w3t_sw,
                        const float* __restrict__ b3, __bf16* __restrict__ b3t_sw,
                        const float* __restrict__ w2, __bf16* __restrict__ w2t_sw,
                        const float* __restrict__ cw1, __bf16* __restrict__ cmw1_sw,
                        const float* __restrict__ x, const float* __restrict__ fc1w,
                        const float* __restrict__ fc1b, const float* __restrict__ cinit,
                        float* __restrict__ h, float* __restrict__ coord,
                        const int* __restrict__ eidx,
                        int* __restrict__ deg, int* __restrict__ within,
                        int* __restrict__ degc, int* __restrict__ withinc) {
    int t = blockIdx.x * blockDim.x + threadIdx.x;
    if (t < 131072) {
        // A-frags for rT-GEMM: entry (ut,l,jj) -> w3 element for
        // (u = ut*16 + (l&15), j2 = ((l>>4)&3)*8 + jj), flat r-index u decodes
        // (c,i): c=(f&3)*32+((ll>>4)&3)*8+j0, i=(f>>2)*16+(ll&15).
        int jj = t & 7, l = (t >> 3) & 63, ut = t >> 9;
        int u  = ut*16 + (l & 15);
        int j2 = ((l >> 4) & 3)*8 + jj;
        int f  = u >> 9, ll = (u >> 3) & 63, j0 = u & 7;
        int c  = (f & 3)*32 + ((ll >> 4) & 3)*8 + j0;
        int i  = (f >> 2)*16 + (ll & 15);
        w3t_sw[t] = (__bf16)w3[c*1024 + i*32 + j2];
    } else if (t < 132096) {
        int idx = t - 131072;
        int jj = idx & 7, l = (idx >> 3) & 63, tt = idx >> 9;
        int i  = tt*16 + (l & 15);
        int j2 = ((l >> 4) & 3)*8 + jj;
        b3t_sw[idx] = (__bf16)b3[i*32 + j2];
    } else if (t < 140288) {
        // A-frags for k2T = w2^T @ k1^T: (ct,ks,l,jj) -> w2[ch][c]
        int idx = t - 132096;
        int jj = idx & 7, l = (idx >> 3) & 63, g = idx >> 9;
        int ct = g >> 1, ks = g & 1;
        int c  = ct*16 + (l & 15);
        int ch = ks*32 + ((l >> 4) & 3)*8 + jj;
        w2t_sw[idx] = (__bf16)w2[ch*128 + c];
    } else if (t < 142336) {
        // B-frags for phi MFMA: (ot,l,jj) -> cm_w1[i][o]
        int idx = t - 140288;
        int jj = idx & 7, l = (idx >> 3) & 63, ot = idx >> 9;
        int o  = ot*16 + (l & 15);
        int i  = ((l >> 4) & 3)*8 + jj;
        cmw1_sw[idx] = (__bf16)cw1[i*32 + o];
    } else if (t < 142336 + NN) {
        int n = t - 142336;
        float x0 = x[n*3+0], x1 = x[n*3+1], x2 = x[n*3+2];
        #pragma unroll
        for (int j = 0; j < 32; j += 4) {
            f32x4 a = *(const f32x4*)(fc1b + j);
            a += x0 * (*(const f32x4*)(fc1w + 0*32 + j));
            a += x1 * (*(const f32x4*)(fc1w + 1*32 + j));
            a += x2 * (*(const f32x4*)(fc1w + 2*32 + j));
            *(f32x4*)(h + n*32 + j) = a;   // no relu on fc1 (matches reference)
        }
        coord[n*3+0] = cinit[n*3+0];
        coord[n*3+1] = cinit[n*3+1];
        coord[n*3+2] = cinit[n*3+2];
    } else if (t < 142336 + NN + NE) {
        int e = t - 142336 - NN;
        within[e] = atomicAdd(&deg[eidx[e]], 1);
    } else if (t < 142336 + NN + 2*NE) {
        int e = t - 142336 - NN - NE;
        withinc[e] = atomicAdd(&degc[eidx[NE + e]], 1);
    }
}

// One fused barrier ladder computing all three exclusive scans at once:
// row CSR (deg), col CSR (degc), segment scan+fill. 1 block x 1024 threads.
__global__ __launch_bounds__(1024, 1)
void k_scan(const int* __restrict__ deg, int* __restrict__ rowptr,
            float* __restrict__ deg_inv,
            const int* __restrict__ degc, int* __restrict__ colptr,
            int* __restrict__ seg_meta, int* __restrict__ seg_start) {
    __shared__ int s0a[1024], s1a[1024], s2a[1024];
    const int tid = threadIdx.x;
    const int CH = 10;                       // 1024*10 >= 10000
    const int base = tid * CH;

    int a = 0, b = 0, c = 0;
    for (int i = 0; i < CH; ++i) {
        int n = base + i;
        if (n < NN) {
            int d0 = deg[n], d1 = degc[n];
            a += d0; b += d1; c += (d1 + 15) >> 4;
        }
    }
    s0a[tid] = a; s1a[tid] = b; s2a[tid] = c;
    __syncthreads();
    for (int off = 1; off < 1024; off <<= 1) {
        int t0 = (tid >= off) ? s0a[tid - off] : 0;
        int t1 = (tid >= off) ? s1a[tid - off] : 0;
        int t2 = (tid >= off) ? s2a[tid - off] : 0;
        __syncthreads();
        s0a[tid] += t0; s1a[tid] += t1; s2a[tid] += t2;
        __syncthreads();
    }
    int run0 = s0a[tid] - a;
    int run1 = s1a[tid] - b;
    int run2 = s2a[tid] - c;
    for (int i = 0; i < CH; ++i) {
        int n = base + i;
        if (n < NN) {
            int d0 = deg[n];
            rowptr[n] = run0; run0 += d0;
            deg_inv[n] = 1.0f / (float)(d0 > 1 ? d0 : 1);
            int d1 = degc[n];
            colptr[n] = run1;
            int ns = (d1 + 15) >> 4;
            for (int k = 0; k < ns; ++k) {
                int cnt = d1 - k*16; if (cnt > 16) cnt = 16;
                seg_meta[run2 + k]  = n | (cnt << 16);
                seg_start[run2 + k] = run1 + k*16;
            }
            run1 += d1; run2 += ns;
        }
    }
    if (tid == 1023) { rowptr[NN] = s0a[1023]; colptr[NN] = s1a[1023]; }
    __syncthreads();
    int nseg = s2a[1023];
    for (int sg = nseg + tid; sg < NSEG_MAX; sg += 1024) {
        seg_meta[sg] = -1;
        seg_start[sg] = 0;
    }
}

// After scans: build col-sorted per-edge arrays (pos, row, pre-gathered attrs).
__global__ void k_setup2(const int* __restrict__ eidx, const float* __restrict__ eattr,
                         const int* __restrict__ rowptr, const int* __restrict__ within,
                         const int* __restrict__ colptr, const int* __restrict__ withinc,
                         int* __restrict__ cs_pos, int* __restrict__ cs_row,
                         float* __restrict__ eattr_cs) {
    int e = blockIdx.x * blockDim.x + threadIdx.x;
    if (e >= NE) return;
    int row = eidx[e], col = eidx[NE + e];
    int pos = rowptr[row] + within[e];
    int cs  = colptr[col] + withinc[e];
    cs_pos[cs] = pos; cs_row[cs] = row;
    #pragma unroll
    for (int a = 0; a < 6; ++a) eattr_cs[(size_t)cs*8 + a] = eattr[(size_t)e*6 + a];
    eattr_cs[(size_t)cs*8 + 6] = 0.f; eattr_cs[(size_t)cs*8 + 7] = 0.f;
}

// ---------------- the fused per-layer edge kernel ----------------
// Round-11 skeleton (301.6 us best: full r in 128 KB LDS, ONE barrier) +
// LDS-pipe cuts with the register cap RELAXED:
//  - __launch_bounds__(1024) only: a 1024-thread block implies <=128 VGPR;
//    dropping the ",4" frees the allocator past the 64-reg pin that made
//    rounds 9/10 spill (FETCH/WRITE are the spill canary).
//  - packed u32 shfls for k2f (64->32 ops) and paf (16->8 ops); math
//    refcheck-passed in rounds 6/7/10.
//  - direct phi store from the owning lane (4 pos-shfls -> 0).
// Shuffle ops/wave 104 -> 60; total LDS ops ~145 -> ~101.
__global__ __launch_bounds__(1024)
void k_edge(const int* __restrict__ seg_meta, const int* __restrict__ seg_start,
            const int* __restrict__ cs_pos, const int* __restrict__ cs_row,
            const float* __restrict__ eattr_cs, const float* __restrict__ coord,
            const float* __restrict__ w1, const float* __restrict__ b1,
            const __bf16* __restrict__ w2t_sw, const float* __restrict__ b2,
            const __bf16* __restrict__ w3t_sw, const __bf16* __restrict__ b3t_sw,
            const float* __restrict__ h,
            const __bf16* __restrict__ cmw1_sw, const float* __restrict__ cm_b1,
            const float* __restrict__ cm_w2,
            float* __restrict__ cds, float* __restrict__ m_s,
            float* __restrict__ phis) {
    __shared__ __align__(16) __bf16 r_lds[16 * 4096];   // 128 KB: FULL r for 16 v
    __shared__ __align__(16) __bf16 wlds[10240];        // 20 KB: w2t + cmw1
    const int tid  = threadIdx.x;
    const int lane = tid & 63;
    const int wave = tid >> 6;                          // 0..15 = segment slot
    const int q  = lane >> 4;
    const int el = lane & 15;
    const int sb = blockIdx.x * 16;
    if (seg_meta[sb] < 0) return;                       // packed: uniform exit

    // stage w2t (16 KB) + cmw1 (4 KB) into LDS
    {
        ((f32x4*)wlds)[tid] = ((const f32x4*)w2t_sw)[tid];
        if (tid < 256) ((f32x4*)(wlds + 8192))[tid] = ((const f32x4*)cmw1_sw)[tid];
    }

    // segment metadata
    const int mown = seg_meta[sb + wave];
    const bool live = mown >= 0;
    const int v_own = live ? (mown & 0xFFFF) : 0;
    const int cnt   = mown >> 16;                       // <0 if dead
    int start = seg_start[sb + wave];

    // B-frag for r-GEMM: col el = h[v_el][q*8 + jj]
    const int mel = seg_meta[sb + el];
    const int vel = (mel < 0) ? 0 : (mel & 0xFFFF);
    bf16x8 bfrag;
    {
        const float* hp = h + (size_t)vel * 32 + q * 8;
        f32x4 h0 = *(const f32x4*)hp;
        f32x4 h1 = *(const f32x4*)(hp + 4);
        bfrag[0]=(__bf16)h0.x; bfrag[1]=(__bf16)h0.y; bfrag[2]=(__bf16)h0.z; bfrag[3]=(__bf16)h0.w;
        bfrag[4]=(__bf16)h1.x; bfrag[5]=(__bf16)h1.y; bfrag[6]=(__bf16)h1.z; bfrag[7]=(__bf16)h1.w;
    }

    // own-edge data (issued early; latency hides under the r-GEMM)
    int slot = start + el; if (slot >= NE) slot = NE - 1;
    const int pos   = cs_pos[slot];
    const int rnode = cs_row[slot];
    const float dx = coord[rnode*3+0] - coord[v_own*3+0];
    const float dy = coord[rnode*3+1] - coord[v_own*3+1];
    const float dz = coord[rnode*3+2] - coord[v_own*3+2];
    const float rad = dx*dx + dy*dy + dz*dz;
    f32x4 ea0 = *(const f32x4*)(eattr_cs + (size_t)slot*8);
    f32x4 ea1 = *(const f32x4*)(eattr_cs + (size_t)slot*8 + 4);
    const float kin[7] = {ea0.x, ea0.y, ea0.z, ea0.w, ea1.x, ea1.y, rad};

    const f32x4 zero = {0.f, 0.f, 0.f, 0.f};

    // full r-GEMM: 16 ut-tiles per wave, all 16 v cols, all 8 frag groups.
    {
        #pragma unroll
        for (int s = 0; s < 16; ++s) {
            const int idx = wave*16 + s;             // 0..255
            const int f = idx >> 5, g = idx & 31;
            bf16x8 af = *(const bf16x8*)(w3t_sw + ((size_t)(f*32 + g)*64 + lane)*8);
            f32x4 c = __builtin_amdgcn_mfma_f32_16x16x32_bf16(af, bfrag, zero, 0, 0, 0);
            const int wb = el*8192 + ((f*1024 + g*32 + q*8) ^ ((el & 7) << 4));
            *(uint2*)((char*)r_lds + wb) = make_uint2(pk2(c.x, c.y), pk2(c.z, c.w));
        }
    }

    // ---- k1: lane computes channels {ks*32 + q*8 + jj} for its own edge el ----
    bf16x8 k1f[2];
    #pragma unroll
    for (int ks = 0; ks < 2; ++ks) {
        const int c0 = ks*32 + q*8;
        f32x4 a0 = *(const f32x4*)(b1 + c0);
        f32x4 a1 = *(const f32x4*)(b1 + c0 + 4);
        #pragma unroll
        for (int a = 0; a < 7; ++a) {
            const float kv = kin[a];
            a0 += kv * (*(const f32x4*)(w1 + a*64 + c0));
            a1 += kv * (*(const f32x4*)(w1 + a*64 + c0 + 4));
        }
        a0 = relu4(a0); a1 = relu4(a1);
        bf16x8 t;
        t[0]=(__bf16)a0.x; t[1]=(__bf16)a0.y; t[2]=(__bf16)a0.z; t[3]=(__bf16)a0.w;
        t[4]=(__bf16)a1.x; t[5]=(__bf16)a1.y; t[6]=(__bf16)a1.z; t[7]=(__bf16)a1.w;
        k1f[ks] = t;
    }

    __syncthreads();                // the ONLY barrier: wlds + full r ready

    // ---- k2T[c x e]: 8 c-tiles; lane holds (c = ct*16+q*4+r, e = el) ----
    f32x4 C2[8];
    #pragma unroll
    for (int ct = 0; ct < 8; ++ct) {
        f32x4 acc = zero;
        #pragma unroll
        for (int ks = 0; ks < 2; ++ks) {
            bf16x8 af = *(const bf16x8*)(wlds + ((ct*2 + ks)*64 + lane)*8);
            acc = __builtin_amdgcn_mfma_f32_16x16x32_bf16(af, k1f[ks], acc, 0, 0, 0);
        }
        f32x4 bb = *(const f32x4*)(b2 + ct*16 + q*4);
        C2[ct] = relu4(acc + bb);
    }

    // ---- B-frags k2T[c = ks2*32+q*8+jj][e = el] via PACKED u32 shfl ----
    const int lowq = q & 1, hiq = q >> 1;
    bf16x8 k2f[4];
    #pragma unroll
    for (int ks2 = 0; ks2 < 4; ++ks2) {
        unsigned pp_[4];
        #pragma unroll
        for (int rr = 0; rr < 4; ++rr)
            pp_[rr] = pk2(C2[ks2*2][rr], C2[ks2*2+1][rr]);   // lo = x0, hi = x1
        unsigned w[4];
        #pragma unroll
        for (int hh = 0; hh < 2; ++hh) {
            const int src = (lowq*2 + hh)*16 + el;
            unsigned e0 = (unsigned)__shfl((int)pp_[0], src, 64);
            unsigned e1 = (unsigned)__shfl((int)pp_[1], src, 64);
            unsigned e2 = (unsigned)__shfl((int)pp_[2], src, 64);
            unsigned e3 = (unsigned)__shfl((int)pp_[3], src, 64);
            if (hiq) { e0 >>= 16; e1 >>= 16; e2 >>= 16; e3 >>= 16; }
            else     { e0 &= 0xFFFFu; e1 &= 0xFFFFu; e2 &= 0xFFFFu; e3 &= 0xFFFFu; }
            w[hh*2+0] = e0 | (e1 << 16);                 // elems hh*4+0, hh*4+1
            w[hh*2+1] = e2 | (e3 << 16);                 // elems hh*4+2, hh*4+3
        }
        u32x4 wv = {w[0], w[1], w[2], w[3]};
        k2f[ks2] = __builtin_bit_cast(bf16x8, wv);
    }

    // ---- m: M[f>>2] += rA[f] x k2f[f&3], f = 0..7 (one rA load at a time) ----
    f32x4 M0 = zero, M1 = zero;
    #pragma unroll
    for (int f = 0; f < 8; ++f) {
        const int rb = wave*8192 + ((f*1024 + lane*16) ^ ((wave & 7) << 4));
        bf16x8 rA = *(const bf16x8*)((const char*)r_lds + rb);
        if (f < 4) M0 = __builtin_amdgcn_mfma_f32_16x16x32_bf16(rA, k2f[f & 3], M0, 0, 0, 0);
        else       M1 = __builtin_amdgcn_mfma_f32_16x16x32_bf16(rA, k2f[f & 3], M1, 0, 0, 0);
    }

    // ---- bt[v][i] via 2 MFMAs + producer-lane shfl (col = wave) ----
    {
        bf16x8 a0 = *(const bf16x8*)(b3t_sw + ((size_t)0*64 + lane)*8);
        bf16x8 a1 = *(const bf16x8*)(b3t_sw + ((size_t)1*64 + lane)*8);
        f32x4 bt0 = __builtin_amdgcn_mfma_f32_16x16x32_bf16(a0, bfrag, zero, 0, 0, 0);
        f32x4 bt1 = __builtin_amdgcn_mfma_f32_16x16x32_bf16(a1, bfrag, zero, 0, 0, 0);
        f32x4 btv0, btv1;
        #pragma unroll
        for (int r = 0; r < 4; ++r) {
            btv0[r] = __shfl(bt0[r], (lane & 48) + wave, 64);
            btv1[r] = __shfl(bt1[r], (lane & 48) + wave, 64);
        }
        M0 += btv0; M1 += btv1;
    }

    const bool ev = live && (el < cnt);
    if (ev) {
        *(f32x4*)(m_s + (size_t)pos*32 + q*4)      = M0;
        *(f32x4*)(m_s + (size_t)pos*32 + 16 + q*4) = M1;
        if (q == 0) {
            f32x4 cdv = {dx, dy, dz, rad};
            *(f32x4*)(cds + (size_t)pos*4) = cdv;
        }
    }

    // ---- phi: A-frag m[e = el][i = q*8+jj] via PACKED u32 shfl, 2 MFMAs ----
    bf16x8 paf;
    {
        unsigned pm[4];
        #pragma unroll
        for (int rr = 0; rr < 4; ++rr)
            pm[rr] = pk2(M0[rr], M1[rr]);                // lo = M0, hi = M1
        unsigned w[4];
        #pragma unroll
        for (int hh = 0; hh < 2; ++hh) {
            const int src = (lowq*2 + hh)*16 + el;
            unsigned e0 = (unsigned)__shfl((int)pm[0], src, 64);
            unsigned e1 = (unsigned)__shfl((int)pm[1], src, 64);
            unsigned e2 = (unsigned)__shfl((int)pm[2], src, 64);
            unsigned e3 = (unsigned)__shfl((int)pm[3], src, 64);
            if (hiq) { e0 >>= 16; e1 >>= 16; e2 >>= 16; e3 >>= 16; }
            else     { e0 &= 0xFFFFu; e1 &= 0xFFFFu; e2 &= 0xFFFFu; e3 &= 0xFFFFu; }
            w[hh*2+0] = e0 | (e1 << 16);
            w[hh*2+1] = e2 | (e3 << 16);
        }
        u32x4 wv = {w[0], w[1], w[2], w[3]};
        paf = __builtin_bit_cast(bf16x8, wv);
    }
    bf16x8 bf0 = *(const bf16x8*)(wlds + 8192 + (0*64 + lane)*8);
    bf16x8 bf1 = *(const bf16x8*)(wlds + 8192 + (1*64 + lane)*8);
    f32x4 PH0 = __builtin_amdgcn_mfma_f32_16x16x32_bf16(paf, bf0, zero, 0, 0, 0);
    f32x4 PH1 = __builtin_amdgcn_mfma_f32_16x16x32_bf16(paf, bf1, zero, 0, 0, 0);

    const float b1v0 = cm_b1[el], b1v1 = cm_b1[16 + el];
    const float w2v0 = cm_w2[el], w2v1 = cm_w2[16 + el];
    float ph[4];
    #pragma unroll
    for (int r = 0; r < 4; ++r) {
        float s0 = fmaxf(PH0[r] + b1v0, 0.f) * w2v0
                 + fmaxf(PH1[r] + b1v1, 0.f) * w2v1;
        s0 += __shfl_xor(s0, 1, 64);
        s0 += __shfl_xor(s0, 2, 64);
        s0 += __shfl_xor(s0, 4, 64);
        s0 += __shfl_xor(s0, 8, 64);
        ph[r] = s0;                      // phi of edge q*4+r, uniform across el
    }
    // direct store: lane (q, el = q*4+r) owns edge el and already holds its pos
    if (live && (el >> 2) == q && el < cnt)
        phis[pos] = ph[el & 3];
}

// CSR gather over SORTED buffers (contiguous streams). 8 threads/node.
// m-sum: 4-deep independent accumulators (MLP). phi*cd: parallel across all
// 8 subs + 3-level xor-reduce. dofinal: fused output MLP via shfl.
__global__ __launch_bounds__(256, 4)
void k_gather(const int* __restrict__ rowptr,
              const float* __restrict__ m_s, const float* __restrict__ phis,
              const float* __restrict__ cds, const float* __restrict__ deg_inv,
              float* __restrict__ coord, float* __restrict__ h,
              const float* __restrict__ fw1, const float* __restrict__ fb1,
              const float* __restrict__ fw2, const float* __restrict__ fb2,
              float* __restrict__ out, int dofinal) {
    int tid = blockIdx.x * blockDim.x + threadIdx.x;
    int n = tid >> 3, sub = tid & 7;
    if (n >= NN) return;
    int st = rowptr[n], en = rowptr[n+1];
    f32x4 am0 = {0.f, 0.f, 0.f, 0.f}, am1 = {0.f, 0.f, 0.f, 0.f};
    f32x4 am2 = {0.f, 0.f, 0.f, 0.f}, am3 = {0.f, 0.f, 0.f, 0.f};
    int p = st;
    for (; p + 3 < en; p += 4) {
        am0 += *(const f32x4*)(m_s + (size_t)p*32 + sub*4);
        am1 += *(const f32x4*)(m_s + (size_t)(p+1)*32 + sub*4);
        am2 += *(const f32x4*)(m_s + (size_t)(p+2)*32 + sub*4);
        am3 += *(const f32x4*)(m_s + (size_t)(p+3)*32 + sub*4);
    }
    for (; p < en; ++p)
        am0 += *(const f32x4*)(m_s + (size_t)p*32 + sub*4);
    f32x4 am = (am0 + am1) + (am2 + am3);

    float di = deg_inv[n];
    f32x4 hv = *(const f32x4*)(h + (size_t)n*32 + sub*4);
    hv = relu4(hv + am * di);

    // phi*cd: each sub handles edges st+sub, st+sub+8, ...; 3-level reduce
    float cx = 0.f, cy = 0.f, cz = 0.f;
    for (int pp = st + sub; pp < en; pp += 8) {
        f32x4 cd = *(const f32x4*)(cds + (size_t)pp*4);
        float ph = phis[pp];
        cx += cd.x * ph; cy += cd.y * ph; cz += cd.z * ph;
    }
    cx += __shfl_xor(cx, 1, 64); cy += __shfl_xor(cy, 1, 64); cz += __shfl_xor(cz, 1, 64);
    cx += __shfl_xor(cx, 2, 64); cy += __shfl_xor(cy, 2, 64); cz += __shfl_xor(cz, 2, 64);
    cx += __shfl_xor(cx, 4, 64); cy += __shfl_xor(cy, 4, 64); cz += __shfl_xor(cz, 4, 64);
    float c0 = 0.f, c1 = 0.f, c2 = 0.f;
    if (sub == 0) {
        c0 = coord[n*3+0] + cx * di;
        c1 = coord[n*3+1] + cy * di;
        c2 = coord[n*3+2] + cz * di;
    }

    if (!dofinal) {
        *(f32x4*)(h + (size_t)n*32 + sub*4) = hv;
        if (sub == 0) {
            coord[n*3+0] = c0; coord[n*3+1] = c1; coord[n*3+2] = c2;
        }
        return;
    }

    const int gbase = (tid & 63) & 56;
    float hreg[32];
    #pragma unroll
    for (int s2 = 0; s2 < 8; ++s2) {
        hreg[s2*4+0] = __shfl(hv.x, gbase + s2, 64);
        hreg[s2*4+1] = __shfl(hv.y, gbase + s2, 64);
        hreg[s2*4+2] = __shfl(hv.z, gbase + s2, 64);
        hreg[s2*4+3] = __shfl(hv.w, gbase + s2, 64);
    }
    float po = 0.f;
    #pragma unroll
    for (int oo = 0; oo < 8; oo += 4) {
        int o = sub*8 + oo;
        f32x4 a = *(const f32x4*)(fb1 + o);
        #pragma unroll
        for (int i = 0; i < 32; ++i)
            a += hreg[i] * (*(const f32x4*)(fw1 + i*64 + o));
        a = relu4(a);
        f32x4 w2 = *(const f32x4*)(fw2 + o);
        po += a.x*w2.x + a.y*w2.y + a.z*w2.z + a.w*w2.w;
    }
    po += __shfl_xor(po, 1, 64);
    po += __shfl_xor(po, 2, 64);
    po += __shfl_xor(po, 4, 64);
    if (sub == 0) {
        out[n] = po + fb2[0];
        out[NN + n*3 + 0] = c0;
        out[NN + n*3 + 1] = c1;
        out[NN + n*3 + 2] = c2;
    }
}

// ---------------- launch ----------------

extern "C" void kernel_launch(void* const* d_in, const int* in_sizes, int n_in,
                              void* d_out, int out_size, void* d_ws, size_t ws_size,
                              hipStream_t stream) {
    const float* x      = (const float*)d_in[0];
    const int*   eidx   = (const int*)  d_in[1];
    const float* eattr  = (const float*)d_in[2];
    const float* cinit  = (const float*)d_in[3];
    const float* fc1w   = (const float*)d_in[4];
    const float* fc1b   = (const float*)d_in[5];
    const float* kw1    = (const float*)d_in[6];
    const float* kb1    = (const float*)d_in[7];
    const float* kw2    = (const float*)d_in[8];
    const float* kb2    = (const float*)d_in[9];
    const float* kw3    = (const float*)d_in[10];
    const float* kb3    = (const float*)d_in[11];
    const float* cmw1   = (const float*)d_in[12];
    const float* cmb1   = (const float*)d_in[13];
    const float* cmw2   = (const float*)d_in[14];
    const float* f2w1   = (const float*)d_in[15];
    const float* f2b1   = (const float*)d_in[16];
    const float* f2w2   = (const float*)d_in[17];
    const float* f2b2   = (const float*)d_in[18];
    float* out = (float*)d_out;

    char* p = (char*)d_ws;
    auto carve = [&](size_t bytes) {
        void* r = (void*)p;
        p += (bytes + 255) & ~(size_t)255;
        return r;
    };
    float*  h        = (float*) carve((size_t)NN * 32 * 4);
    float*  coord    = (float*) carve((size_t)NN * 3 * 4);
    int*    deg      = (int*)   carve((size_t)NN * 4);
    float*  deg_inv  = (float*) carve((size_t)NN * 4);
    int*    rowptr   = (int*)   carve((size_t)(NN + 1) * 4);
    int*    within   = (int*)   carve((size_t)NE * 4);
    int*    degc     = (int*)   carve((size_t)NN * 4);
    int*    colptr   = (int*)   carve((size_t)(NN + 1) * 4);
    int*    withinc  = (int*)   carve((size_t)NE * 4);
    int*    cs_pos   = (int*)   carve((size_t)NE * 4);
    int*    cs_row   = (int*)   carve((size_t)NE * 4);
    float*  eattr_cs = (float*) carve((size_t)NE * 8 * 4);
    int*    seg_meta = (int*)   carve((size_t)NSEG_MAX * 4);
    int*    seg_start= (int*)   carve((size_t)NSEG_MAX * 4);
    float*  cds      = (float*) carve((size_t)NE * 4 * 4);
    float*  m_s      = (float*) carve((size_t)NE * 32 * 4);
    float*  phis     = (float*) carve((size_t)NE * 4);
    __bf16* w3t_sw   = (__bf16*)carve((size_t)131072 * 2);
    __bf16* b3t_sw   = (__bf16*)carve((size_t)1024 * 2);
    __bf16* w2t_sw   = (__bf16*)carve((size_t)8192 * 2);
    __bf16* cmw1_sw  = (__bf16*)carve((size_t)2048 * 2);

    const int TB = 256;
    dim3 b(TB);
    const int totS = 142336 + NN + 2*NE;
    dim3 gS((totS + TB - 1) / TB);
    dim3 gS2((NE + TB - 1) / TB);
    dim3 gE(NSEG_MAX / 16);       // 16 segments per 1024-thread block
    dim3 gA((NN*8 + TB - 1) / TB);

    hipMemsetAsync(deg, 0, (size_t)NN * 4, stream);
    hipMemsetAsync(degc, 0, (size_t)NN * 4, stream);
    k_setup<<<gS, b, 0, stream>>>(kw3, w3t_sw, kb3, b3t_sw, kw2, w2t_sw, cmw1, cmw1_sw,
                                  x, fc1w, fc1b, cinit, h, coord, eidx,
                                  deg, within, degc, withinc);
    k_scan<<<1, dim3(1024), 0, stream>>>(deg, rowptr, deg_inv, degc, colptr,
                                         seg_meta, seg_start);
    k_setup2<<<gS2, b, 0, stream>>>(eidx, eattr, rowptr, within, colptr, withinc,
                                    cs_pos, cs_row, eattr_cs);

    for (int d = 0; d < 3; ++d) {
        k_edge<<<gE, dim3(1024), 0, stream>>>(seg_meta, seg_start, cs_pos, cs_row,
                                              eattr_cs, coord, kw1, kb1, w2t_sw, kb2,
                                              w3t_sw, b3t_sw, h, cmw1_sw, cmb1, cmw2,
                                              cds, m_s, phis);
        k_gather<<<gA, b, 0, stream>>>(rowptr, m_s, phis, cds, deg_inv, coord, h,
                                       f2w1, f2b1, f2w2, f2b2, out, d == 2 ? 1 : 0);
    }
}

// Round 13
// 300.108 us; speedup vs baseline: 1.0204x; 1.0204x over previous
//
#include <hip/hip_runtime.h>
#include <hip/hip_bf16.h>

#define NN 10000
#define NE 100000
#define NSEG_MAX 16384   // >= sum_v ceil(degc/16) <= (E + 15N)/16 = 15625

typedef __bf16 bf16x8 __attribute__((ext_vector_type(8)));
typedef float  f32x4  __attribute__((ext_vector_type(4)));
typedef float  f32x2  __attribute__((ext_vector_type(2)));

__device__ __forceinline__ f32x4 relu4(f32x4 a) {
    a.x = fmaxf(a.x, 0.f); a.y = fmaxf(a.y, 0.f);
    a.z = fmaxf(a.z, 0.f); a.w = fmaxf(a.w, 0.f);
    return a;
}

__device__ __forceinline__ unsigned pk2(float a, float b) {
    unsigned ua = (unsigned)__builtin_bit_cast(unsigned short, (__bf16)a);
    unsigned ub = (unsigned)__builtin_bit_cast(unsigned short, (__bf16)b);
    return ua | (ub << 16);
}

// ---------------- one-time kernels ----------------
// Swizzle tables (all MFMA-frag layouts), h/coord init, row+col degree counts.
__global__ void k_setup(const float* __restrict__ w3, __bf16* __restrict__ w3t_sw,
                        const float* __restrict__ b3, __bf16* __restrict__ b3t_sw,
                        const float* __restrict__ w2, __bf16* __restrict__ w2t_sw,
                        const float* __restrict__ cw1, __bf16* __restrict__ cmw1_sw,
                        const float* __restrict__ x, const float* __restrict__ fc1w,
                        const float* __restrict__ fc1b, const float* __restrict__ cinit,
                        float* __restrict__ h, float* __restrict__ coord,
                        const int* __restrict__ eidx,
                        int* __restrict__ deg, int* __restrict__ within,
                        int* __restrict__ degc, int* __restrict__ withinc) {
    int t = blockIdx.x * blockDim.x + threadIdx.x;
    if (t < 131072) {
        // A-frags for rT-GEMM: entry (ut,l,jj) -> w3 element for
        // (u = ut*16 + (l&15), j2 = ((l>>4)&3)*8 + jj), flat r-index u decodes
        // (c,i): c=(f&3)*32+((ll>>4)&3)*8+j0, i=(f>>2)*16+(ll&15).
        int jj = t & 7, l = (t >> 3) & 63, ut = t >> 9;
        int u  = ut*16 + (l & 15);
        int j2 = ((l >> 4) & 3)*8 + jj;
        int f  = u >> 9, ll = (u >> 3) & 63, j0 = u & 7;
        int c  = (f & 3)*32 + ((ll >> 4) & 3)*8 + j0;
        int i  = (f >> 2)*16 + (ll & 15);
        w3t_sw[t] = (__bf16)w3[c*1024 + i*32 + j2];
    } else if (t < 132096) {
        int idx = t - 131072;
        int jj = idx & 7, l = (idx >> 3) & 63, tt = idx >> 9;
        int i  = tt*16 + (l & 15);
        int j2 = ((l >> 4) & 3)*8 + jj;
        b3t_sw[idx] = (__bf16)b3[i*32 + j2];
    } else if (t < 140288) {
        // A-frags for k2T = w2^T @ k1^T: (ct,ks,l,jj) -> w2[ch][c]
        int idx = t - 132096;
        int jj = idx & 7, l = (idx >> 3) & 63, g = idx >> 9;
        int ct = g >> 1, ks = g & 1;
        int c  = ct*16 + (l & 15);
        int ch = ks*32 + ((l >> 4) & 3)*8 + jj;
        w2t_sw[idx] = (__bf16)w2[ch*128 + c];
    } else if (t < 142336) {
        // B-frags for phi MFMA: (ot,l,jj) -> cm_w1[i][o]
        int idx = t - 140288;
        int jj = idx & 7, l = (idx >> 3) & 63, ot = idx >> 9;
        int o  = ot*16 + (l & 15);
        int i  = ((l >> 4) & 3)*8 + jj;
        cmw1_sw[idx] = (__bf16)cw1[i*32 + o];
    } else if (t < 142336 + NN) {
        int n = t - 142336;
        float x0 = x[n*3+0], x1 = x[n*3+1], x2 = x[n*3+2];
        #pragma unroll
        for (int j = 0; j < 32; j += 4) {
            f32x4 a = *(const f32x4*)(fc1b + j);
            a += x0 * (*(const f32x4*)(fc1w + 0*32 + j));
            a += x1 * (*(const f32x4*)(fc1w + 1*32 + j));
            a += x2 * (*(const f32x4*)(fc1w + 2*32 + j));
            *(f32x4*)(h + n*32 + j) = a;   // no relu on fc1 (matches reference)
        }
        coord[n*3+0] = cinit[n*3+0];
        coord[n*3+1] = cinit[n*3+1];
        coord[n*3+2] = cinit[n*3+2];
    } else if (t < 142336 + NN + NE) {
        int e = t - 142336 - NN;
        within[e] = atomicAdd(&deg[eidx[e]], 1);
    } else if (t < 142336 + NN + 2*NE) {
        int e = t - 142336 - NN - NE;
        withinc[e] = atomicAdd(&degc[eidx[NE + e]], 1);
    }
}

// One fused barrier ladder computing all three exclusive scans at once:
// row CSR (deg), col CSR (degc), segment scan+fill. 1 block x 1024 threads.
__global__ __launch_bounds__(1024, 1)
void k_scan(const int* __restrict__ deg, int* __restrict__ rowptr,
            float* __restrict__ deg_inv,
            const int* __restrict__ degc, int* __restrict__ colptr,
            int* __restrict__ seg_meta, int* __restrict__ seg_start) {
    __shared__ int s0a[1024], s1a[1024], s2a[1024];
    const int tid = threadIdx.x;
    const int CH = 10;                       // 1024*10 >= 10000
    const int base = tid * CH;

    int a = 0, b = 0, c = 0;
    for (int i = 0; i < CH; ++i) {
        int n = base + i;
        if (n < NN) {
            int d0 = deg[n], d1 = degc[n];
            a += d0; b += d1; c += (d1 + 15) >> 4;
        }
    }
    s0a[tid] = a; s1a[tid] = b; s2a[tid] = c;
    __syncthreads();
    for (int off = 1; off < 1024; off <<= 1) {
        int t0 = (tid >= off) ? s0a[tid - off] : 0;
        int t1 = (tid >= off) ? s1a[tid - off] : 0;
        int t2 = (tid >= off) ? s2a[tid - off] : 0;
        __syncthreads();
        s0a[tid] += t0; s1a[tid] += t1; s2a[tid] += t2;
        __syncthreads();
    }
    int run0 = s0a[tid] - a;
    int run1 = s1a[tid] - b;
    int run2 = s2a[tid] - c;
    for (int i = 0; i < CH; ++i) {
        int n = base + i;
        if (n < NN) {
            int d0 = deg[n];
            rowptr[n] = run0; run0 += d0;
            deg_inv[n] = 1.0f / (float)(d0 > 1 ? d0 : 1);
            int d1 = degc[n];
            colptr[n] = run1;
            int ns = (d1 + 15) >> 4;
            for (int k = 0; k < ns; ++k) {
                int cnt = d1 - k*16; if (cnt > 16) cnt = 16;
                seg_meta[run2 + k]  = n | (cnt << 16);
                seg_start[run2 + k] = run1 + k*16;
            }
            run1 += d1; run2 += ns;
        }
    }
    if (tid == 1023) { rowptr[NN] = s0a[1023]; colptr[NN] = s1a[1023]; }
    __syncthreads();
    int nseg = s2a[1023];
    for (int sg = nseg + tid; sg < NSEG_MAX; sg += 1024) {
        seg_meta[sg] = -1;
        seg_start[sg] = 0;
    }
}

// After scans: build col-sorted per-edge arrays (pos, row, pre-gathered attrs).
__global__ void k_setup2(const int* __restrict__ eidx, const float* __restrict__ eattr,
                         const int* __restrict__ rowptr, const int* __restrict__ within,
                         const int* __restrict__ colptr, const int* __restrict__ withinc,
                         int* __restrict__ cs_pos, int* __restrict__ cs_row,
                         float* __restrict__ eattr_cs) {
    int e = blockIdx.x * blockDim.x + threadIdx.x;
    if (e >= NE) return;
    int row = eidx[e], col = eidx[NE + e];
    int pos = rowptr[row] + within[e];
    int cs  = colptr[col] + withinc[e];
    cs_pos[cs] = pos; cs_row[cs] = row;
    #pragma unroll
    for (int a = 0; a < 6; ++a) eattr_cs[(size_t)cs*8 + a] = eattr[(size_t)e*6 + a];
    eattr_cs[(size_t)cs*8 + 6] = 0.f; eattr_cs[(size_t)cs*8 + 7] = 0.f;
}

// ---------------- the fused per-layer edge kernel ----------------
// VERBATIM round-11 winner (301.6 us total, k_edge 49.2 us, spill-free):
// full r in 128 KB LDS (16 v x 8 KB), ONE barrier, float shfls.
// Lessons locked in: any added register pressure spills at the compiler's
// pinned 64-VGPR allocation (r9/r10/r12); occupancy cannot be raised (r10).
__global__ __launch_bounds__(1024, 4)
void k_edge(const int* __restrict__ seg_meta, const int* __restrict__ seg_start,
            const int* __restrict__ cs_pos, const int* __restrict__ cs_row,
            const float* __restrict__ eattr_cs, const float* __restrict__ coord,
            const float* __restrict__ w1, const float* __restrict__ b1,
            const __bf16* __restrict__ w2t_sw, const float* __restrict__ b2,
            const __bf16* __restrict__ w3t_sw, const __bf16* __restrict__ b3t_sw,
            const float* __restrict__ h,
            const __bf16* __restrict__ cmw1_sw, const float* __restrict__ cm_b1,
            const float* __restrict__ cm_w2,
            float* __restrict__ cds, float* __restrict__ m_s,
            float* __restrict__ phis) {
    __shared__ __align__(16) __bf16 r_lds[16 * 4096];   // 128 KB: FULL r for 16 v
    __shared__ __align__(16) __bf16 wlds[10240];        // 20 KB: w2t + cmw1
    const int tid  = threadIdx.x;
    const int lane = tid & 63;
    const int wave = tid >> 6;                          // 0..15 = segment slot
    const int q  = lane >> 4;
    const int el = lane & 15;
    const int sb = blockIdx.x * 16;
    if (seg_meta[sb] < 0) return;                       // packed: uniform exit

    // stage w2t (16 KB) + cmw1 (4 KB) into LDS
    {
        ((f32x4*)wlds)[tid] = ((const f32x4*)w2t_sw)[tid];
        if (tid < 256) ((f32x4*)(wlds + 8192))[tid] = ((const f32x4*)cmw1_sw)[tid];
    }

    // segment metadata
    const int mown = seg_meta[sb + wave];
    const bool live = mown >= 0;
    const int v_own = live ? (mown & 0xFFFF) : 0;
    const int cnt   = mown >> 16;                       // <0 if dead
    int start = seg_start[sb + wave];

    // B-frag for r-GEMM: col el = h[v_el][q*8 + jj]
    const int mel = seg_meta[sb + el];
    const int vel = (mel < 0) ? 0 : (mel & 0xFFFF);
    bf16x8 bfrag;
    {
        const float* hp = h + (size_t)vel * 32 + q * 8;
        f32x4 h0 = *(const f32x4*)hp;
        f32x4 h1 = *(const f32x4*)(hp + 4);
        bfrag[0]=(__bf16)h0.x; bfrag[1]=(__bf16)h0.y; bfrag[2]=(__bf16)h0.z; bfrag[3]=(__bf16)h0.w;
        bfrag[4]=(__bf16)h1.x; bfrag[5]=(__bf16)h1.y; bfrag[6]=(__bf16)h1.z; bfrag[7]=(__bf16)h1.w;
    }

    // own-edge data (issued early; latency hides under phase A)
    int slot = start + el; if (slot >= NE) slot = NE - 1;
    const int pos   = cs_pos[slot];
    const int rnode = cs_row[slot];
    const float dx = coord[rnode*3+0] - coord[v_own*3+0];
    const float dy = coord[rnode*3+1] - coord[v_own*3+1];
    const float dz = coord[rnode*3+2] - coord[v_own*3+2];
    const float rad = dx*dx + dy*dy + dz*dz;
    f32x4 ea0 = *(const f32x4*)(eattr_cs + (size_t)slot*8);
    f32x4 ea1 = *(const f32x4*)(eattr_cs + (size_t)slot*8 + 4);
    const float kin[7] = {ea0.x, ea0.y, ea0.z, ea0.w, ea1.x, ea1.y, rad};

    const f32x4 zero = {0.f, 0.f, 0.f, 0.f};

    // full r-GEMM: 16 ut-tiles per wave, all 16 v cols, all 8 frag groups.
    // wave w covers idx = w*16..w*16+15 -> (f = idx>>5, g = idx&31), each
    // (f,g) exactly once across the block.
    {
        #pragma unroll
        for (int s = 0; s < 16; ++s) {
            const int idx = wave*16 + s;             // 0..255
            const int f = idx >> 5, g = idx & 31;
            bf16x8 af = *(const bf16x8*)(w3t_sw + ((size_t)(f*32 + g)*64 + lane)*8);
            f32x4 c = __builtin_amdgcn_mfma_f32_16x16x32_bf16(af, bfrag, zero, 0, 0, 0);
            const int wb = el*8192 + ((f*1024 + g*32 + q*8) ^ ((el & 7) << 4));
            *(uint2*)((char*)r_lds + wb) = make_uint2(pk2(c.x, c.y), pk2(c.z, c.w));
        }
    }

    // ---- k1: lane computes channels {ks*32 + q*8 + jj} for its own edge el ----
    bf16x8 k1f[2];
    #pragma unroll
    for (int ks = 0; ks < 2; ++ks) {
        const int c0 = ks*32 + q*8;
        f32x4 a0 = *(const f32x4*)(b1 + c0);
        f32x4 a1 = *(const f32x4*)(b1 + c0 + 4);
        #pragma unroll
        for (int a = 0; a < 7; ++a) {
            const float kv = kin[a];
            a0 += kv * (*(const f32x4*)(w1 + a*64 + c0));
            a1 += kv * (*(const f32x4*)(w1 + a*64 + c0 + 4));
        }
        a0 = relu4(a0); a1 = relu4(a1);
        bf16x8 t;
        t[0]=(__bf16)a0.x; t[1]=(__bf16)a0.y; t[2]=(__bf16)a0.z; t[3]=(__bf16)a0.w;
        t[4]=(__bf16)a1.x; t[5]=(__bf16)a1.y; t[6]=(__bf16)a1.z; t[7]=(__bf16)a1.w;
        k1f[ks] = t;
    }

    __syncthreads();                // the ONLY barrier: wlds + full r ready

    // ---- k2T[c x e]: 8 c-tiles; lane holds (c = ct*16+q*4+r, e = el) ----
    f32x4 C2[8];
    #pragma unroll
    for (int ct = 0; ct < 8; ++ct) {
        f32x4 acc = zero;
        #pragma unroll
        for (int ks = 0; ks < 2; ++ks) {
            bf16x8 af = *(const bf16x8*)(wlds + ((ct*2 + ks)*64 + lane)*8);
            acc = __builtin_amdgcn_mfma_f32_16x16x32_bf16(af, k1f[ks], acc, 0, 0, 0);
        }
        f32x4 bb = *(const f32x4*)(b2 + ct*16 + q*4);
        C2[ct] = relu4(acc + bb);
    }

    // ---- B-frags k2T[c = ks2*32+q*8+jj][e = el] via intra-wave shfl ----
    const int lowq = q & 1, hiq = q >> 1;
    bf16x8 k2f[4];
    #pragma unroll
    for (int ks2 = 0; ks2 < 4; ++ks2) {
        bf16x8 t;
        #pragma unroll
        for (int hh = 0; hh < 2; ++hh) {
            const int src = (lowq*2 + hh)*16 + el;
            #pragma unroll
            for (int rr = 0; rr < 4; ++rr) {
                const float x0 = __shfl(C2[ks2*2][rr],     src, 64);
                const float x1 = __shfl(C2[ks2*2 + 1][rr], src, 64);
                t[hh*4 + rr] = (__bf16)(hiq ? x1 : x0);
            }
        }
        k2f[ks2] = t;
    }

    // ---- m: M[f>>2] += rA[f] x k2f[f&3], f = 0..7 (one rA load at a time) ----
    f32x4 M0 = zero, M1 = zero;
    #pragma unroll
    for (int f = 0; f < 8; ++f) {
        const int rb = wave*8192 + ((f*1024 + lane*16) ^ ((wave & 7) << 4));
        bf16x8 rA = *(const bf16x8*)((const char*)r_lds + rb);
        if (f < 4) M0 = __builtin_amdgcn_mfma_f32_16x16x32_bf16(rA, k2f[f & 3], M0, 0, 0, 0);
        else       M1 = __builtin_amdgcn_mfma_f32_16x16x32_bf16(rA, k2f[f & 3], M1, 0, 0, 0);
    }

    // ---- bt[v][i] via 2 MFMAs + producer-lane shfl (col = wave) ----
    {
        bf16x8 a0 = *(const bf16x8*)(b3t_sw + ((size_t)0*64 + lane)*8);
        bf16x8 a1 = *(const bf16x8*)(b3t_sw + ((size_t)1*64 + lane)*8);
        f32x4 bt0 = __builtin_amdgcn_mfma_f32_16x16x32_bf16(a0, bfrag, zero, 0, 0, 0);
        f32x4 bt1 = __builtin_amdgcn_mfma_f32_16x16x32_bf16(a1, bfrag, zero, 0, 0, 0);
        f32x4 btv0, btv1;
        #pragma unroll
        for (int r = 0; r < 4; ++r) {
            btv0[r] = __shfl(bt0[r], (lane & 48) + wave, 64);
            btv1[r] = __shfl(bt1[r], (lane & 48) + wave, 64);
        }
        M0 += btv0; M1 += btv1;
    }

    const bool ev = live && (el < cnt);
    if (ev) {
        *(f32x4*)(m_s + (size_t)pos*32 + q*4)      = M0;
        *(f32x4*)(m_s + (size_t)pos*32 + 16 + q*4) = M1;
        if (q == 0) {
            f32x4 cdv = {dx, dy, dz, rad};
            *(f32x4*)(cds + (size_t)pos*4) = cdv;
        }
    }

    // ---- phi: A-frag m[e = el][i = q*8+jj] via shfl, then 2 MFMAs ----
    bf16x8 paf;
    #pragma unroll
    for (int hh = 0; hh < 2; ++hh) {
        const int src = (lowq*2 + hh)*16 + el;
        #pragma unroll
        for (int rr = 0; rr < 4; ++rr) {
            const float x0 = __shfl(M0[rr], src, 64);
            const float x1 = __shfl(M1[rr], src, 64);
            paf[hh*4 + rr] = (__bf16)(hiq ? x1 : x0);
        }
    }
    bf16x8 bf0 = *(const bf16x8*)(wlds + 8192 + (0*64 + lane)*8);
    bf16x8 bf1 = *(const bf16x8*)(wlds + 8192 + (1*64 + lane)*8);
    f32x4 PH0 = __builtin_amdgcn_mfma_f32_16x16x32_bf16(paf, bf0, zero, 0, 0, 0);
    f32x4 PH1 = __builtin_amdgcn_mfma_f32_16x16x32_bf16(paf, bf1, zero, 0, 0, 0);

    const float b1v0 = cm_b1[el], b1v1 = cm_b1[16 + el];
    const float w2v0 = cm_w2[el], w2v1 = cm_w2[16 + el];
    float ph[4]; int pr[4];
    #pragma unroll
    for (int r = 0; r < 4; ++r) {
        float s0 = fmaxf(PH0[r] + b1v0, 0.f) * w2v0
                 + fmaxf(PH1[r] + b1v1, 0.f) * w2v1;
        s0 += __shfl_xor(s0, 1, 64);
        s0 += __shfl_xor(s0, 2, 64);
        s0 += __shfl_xor(s0, 4, 64);
        s0 += __shfl_xor(s0, 8, 64);
        ph[r] = s0;
        pr[r] = __shfl(pos, (q << 4) + q*4 + r, 64);  // pos of edge q*4+r
    }
    if (live && el == 0) {
        #pragma unroll
        for (int r = 0; r < 4; ++r)
            if (q*4 + r < cnt) phis[pr[r]] = ph[r];
    }
}

// CSR gather, now 16 threads/node (sub owns channels {2*sub, 2*sub+1} via
// float2). 160K threads = ~10 waves/CU (2x the 8-thread version, which ran
// at ~4.9 waves/CU -- occupancy-starved for a scattered-load latency kernel).
// Memory pattern unchanged: 8-B loads, coalesced per 16-lane group per row.
__global__ __launch_bounds__(256, 4)
void k_gather(const int* __restrict__ rowptr,
              const float* __restrict__ m_s, const float* __restrict__ phis,
              const float* __restrict__ cds, const float* __restrict__ deg_inv,
              float* __restrict__ coord, float* __restrict__ h,
              const float* __restrict__ fw1, const float* __restrict__ fb1,
              const float* __restrict__ fw2, const float* __restrict__ fb2,
              float* __restrict__ out, int dofinal) {
    int tid = blockIdx.x * blockDim.x + threadIdx.x;
    int n = tid >> 4, sub = tid & 15;
    if (n >= NN) return;
    int st = rowptr[n], en = rowptr[n+1];
    f32x2 am0 = {0.f, 0.f}, am1 = {0.f, 0.f};
    f32x2 am2 = {0.f, 0.f}, am3 = {0.f, 0.f};
    int p = st;
    for (; p + 3 < en; p += 4) {
        am0 += *(const f32x2*)(m_s + (size_t)p*32 + sub*2);
        am1 += *(const f32x2*)(m_s + (size_t)(p+1)*32 + sub*2);
        am2 += *(const f32x2*)(m_s + (size_t)(p+2)*32 + sub*2);
        am3 += *(const f32x2*)(m_s + (size_t)(p+3)*32 + sub*2);
    }
    for (; p < en; ++p)
        am0 += *(const f32x2*)(m_s + (size_t)p*32 + sub*2);
    f32x2 am = (am0 + am1) + (am2 + am3);

    float di = deg_inv[n];
    f32x2 hv = *(const f32x2*)(h + (size_t)n*32 + sub*2);
    hv.x = fmaxf(hv.x + am.x * di, 0.f);
    hv.y = fmaxf(hv.y + am.y * di, 0.f);

    // phi*cd: each sub handles edges st+sub, st+sub+16, ...; 4-level reduce
    float cx = 0.f, cy = 0.f, cz = 0.f;
    for (int pp = st + sub; pp < en; pp += 16) {
        f32x4 cd = *(const f32x4*)(cds + (size_t)pp*4);
        float ph = phis[pp];
        cx += cd.x * ph; cy += cd.y * ph; cz += cd.z * ph;
    }
    cx += __shfl_xor(cx, 1, 64); cy += __shfl_xor(cy, 1, 64); cz += __shfl_xor(cz, 1, 64);
    cx += __shfl_xor(cx, 2, 64); cy += __shfl_xor(cy, 2, 64); cz += __shfl_xor(cz, 2, 64);
    cx += __shfl_xor(cx, 4, 64); cy += __shfl_xor(cy, 4, 64); cz += __shfl_xor(cz, 4, 64);
    cx += __shfl_xor(cx, 8, 64); cy += __shfl_xor(cy, 8, 64); cz += __shfl_xor(cz, 8, 64);
    float c0 = 0.f, c1 = 0.f, c2 = 0.f;
    if (sub == 0) {
        c0 = coord[n*3+0] + cx * di;
        c1 = coord[n*3+1] + cy * di;
        c2 = coord[n*3+2] + cz * di;
    }

    if (!dofinal) {
        *(f32x2*)(h + (size_t)n*32 + sub*2) = hv;
        if (sub == 0) {
            coord[n*3+0] = c0; coord[n*3+1] = c1; coord[n*3+2] = c2;
        }
        return;
    }

    // fused final MLP: node group = 16 lanes; collect h[0..31] via shfl
    const int gbase = (tid & 63) & 48;
    float hreg[32];
    #pragma unroll
    for (int i = 0; i < 16; ++i) {
        hreg[i*2+0] = __shfl(hv.x, gbase + i, 64);
        hreg[i*2+1] = __shfl(hv.y, gbase + i, 64);
    }
    float po;
    {
        const int o = sub*4;
        f32x4 a = *(const f32x4*)(fb1 + o);
        #pragma unroll
        for (int i = 0; i < 32; ++i)
            a += hreg[i] * (*(const f32x4*)(fw1 + i*64 + o));
        a = relu4(a);
        f32x4 w2 = *(const f32x4*)(fw2 + o);
        po = a.x*w2.x + a.y*w2.y + a.z*w2.z + a.w*w2.w;
    }
    po += __shfl_xor(po, 1, 64);
    po += __shfl_xor(po, 2, 64);
    po += __shfl_xor(po, 4, 64);
    po += __shfl_xor(po, 8, 64);
    if (sub == 0) {
        out[n] = po + fb2[0];
        out[NN + n*3 + 0] = c0;
        out[NN + n*3 + 1] = c1;
        out[NN + n*3 + 2] = c2;
    }
}

// ---------------- launch ----------------

extern "C" void kernel_launch(void* const* d_in, const int* in_sizes, int n_in,
                              void* d_out, int out_size, void* d_ws, size_t ws_size,
                              hipStream_t stream) {
    const float* x      = (const float*)d_in[0];
    const int*   eidx   = (const int*)  d_in[1];
    const float* eattr  = (const float*)d_in[2];
    const float* cinit  = (const float*)d_in[3];
    const float* fc1w   = (const float*)d_in[4];
    const float* fc1b   = (const float*)d_in[5];
    const float* kw1    = (const float*)d_in[6];
    const float* kb1    = (const float*)d_in[7];
    const float* kw2    = (const float*)d_in[8];
    const float* kb2    = (const float*)d_in[9];
    const float* kw3    = (const float*)d_in[10];
    const float* kb3    = (const float*)d_in[11];
    const float* cmw1   = (const float*)d_in[12];
    const float* cmb1   = (const float*)d_in[13];
    const float* cmw2   = (const float*)d_in[14];
    const float* f2w1   = (const float*)d_in[15];
    const float* f2b1   = (const float*)d_in[16];
    const float* f2w2   = (const float*)d_in[17];
    const float* f2b2   = (const float*)d_in[18];
    float* out = (float*)d_out;

    char* p = (char*)d_ws;
    auto carve = [&](size_t bytes) {
        void* r = (void*)p;
        p += (bytes + 255) & ~(size_t)255;
        return r;
    };
    float*  h        = (float*) carve((size_t)NN * 32 * 4);
    float*  coord    = (float*) carve((size_t)NN * 3 * 4);
    int*    deg      = (int*)   carve((size_t)NN * 4);
    float*  deg_inv  = (float*) carve((size_t)NN * 4);
    int*    rowptr   = (int*)   carve((size_t)(NN + 1) * 4);
    int*    within   = (int*)   carve((size_t)NE * 4);
    int*    degc     = (int*)   carve((size_t)NN * 4);
    int*    colptr   = (int*)   carve((size_t)(NN + 1) * 4);
    int*    withinc  = (int*)   carve((size_t)NE * 4);
    int*    cs_pos   = (int*)   carve((size_t)NE * 4);
    int*    cs_row   = (int*)   carve((size_t)NE * 4);
    float*  eattr_cs = (float*) carve((size_t)NE * 8 * 4);
    int*    seg_meta = (int*)   carve((size_t)NSEG_MAX * 4);
    int*    seg_start= (int*)   carve((size_t)NSEG_MAX * 4);
    float*  cds      = (float*) carve((size_t)NE * 4 * 4);
    float*  m_s      = (float*) carve((size_t)NE * 32 * 4);
    float*  phis     = (float*) carve((size_t)NE * 4);
    __bf16* w3t_sw   = (__bf16*)carve((size_t)131072 * 2);
    __bf16* b3t_sw   = (__bf16*)carve((size_t)1024 * 2);
    __bf16* w2t_sw   = (__bf16*)carve((size_t)8192 * 2);
    __bf16* cmw1_sw  = (__bf16*)carve((size_t)2048 * 2);

    const int TB = 256;
    dim3 b(TB);
    const int totS = 142336 + NN + 2*NE;
    dim3 gS((totS + TB - 1) / TB);
    dim3 gS2((NE + TB - 1) / TB);
    dim3 gE(NSEG_MAX / 16);       // 16 segments per 1024-thread block
    dim3 gA((NN*16 + TB - 1) / TB);

    hipMemsetAsync(deg, 0, (size_t)NN * 4, stream);
    hipMemsetAsync(degc, 0, (size_t)NN * 4, stream);
    k_setup<<<gS, b, 0, stream>>>(kw3, w3t_sw, kb3, b3t_sw, kw2, w2t_sw, cmw1, cmw1_sw,
                                  x, fc1w, fc1b, cinit, h, coord, eidx,
                                  deg, within, degc, withinc);
    k_scan<<<1, dim3(1024), 0, stream>>>(deg, rowptr, deg_inv, degc, colptr,
                                         seg_meta, seg_start);
    k_setup2<<<gS2, b, 0, stream>>>(eidx, eattr, rowptr, within, colptr, withinc,
                                    cs_pos, cs_row, eattr_cs);

    for (int d = 0; d < 3; ++d) {
        k_edge<<<gE, dim3(1024), 0, stream>>>(seg_meta, seg_start, cs_pos, cs_row,
                                              eattr_cs, coord, kw1, kb1, w2t_sw, kb2,
                                              w3t_sw, b3t_sw, h, cmw1_sw, cmb1, cmw2,
                                              cds, m_s, phis);
        k_gather<<<gA, b, 0, stream>>>(rowptr, m_s, phis, cds, deg_inv, coord, h,
                                       f2w1, f2b1, f2w2, f2b2, out, d == 2 ? 1 : 0);
    }
}

// Round 14
// 299.670 us; speedup vs baseline: 1.0219x; 1.0015x over previous
//
#include <hip/hip_runtime.h>
#include <hip/hip_bf16.h>

#define NN 10000
#define NE 100000
#define NSEG_MAX 16384   // >= sum_v ceil(degc/16) <= (E + 15N)/16 = 15625

typedef __bf16 bf16x8 __attribute__((ext_vector_type(8)));
typedef float  f32x4  __attribute__((ext_vector_type(4)));
typedef float  f32x2  __attribute__((ext_vector_type(2)));

__device__ __forceinline__ f32x4 relu4(f32x4 a) {
    a.x = fmaxf(a.x, 0.f); a.y = fmaxf(a.y, 0.f);
    a.z = fmaxf(a.z, 0.f); a.w = fmaxf(a.w, 0.f);
    return a;
}

__device__ __forceinline__ unsigned pk2(float a, float b) {
    unsigned ua = (unsigned)__builtin_bit_cast(unsigned short, (__bf16)a);
    unsigned ub = (unsigned)__builtin_bit_cast(unsigned short, (__bf16)b);
    return ua | (ub << 16);
}

// ---------------- one-time kernels ----------------
// Swizzle tables (all MFMA-frag layouts), h/coord init, row+col degree counts.
__global__ void k_setup(const float* __restrict__ w3, __bf16* __restrict__ w3t_sw,
                        const float* __restrict__ b3, __bf16* __restrict__ b3t_sw,
                        const float* __restrict__ w2, __bf16* __restrict__ w2t_sw,
                        const float* __restrict__ cw1, __bf16* __restrict__ cmw1_sw,
                        const float* __restrict__ x, const float* __restrict__ fc1w,
                        const float* __restrict__ fc1b, const float* __restrict__ cinit,
                        float* __restrict__ h, float* __restrict__ coord,
                        const int* __restrict__ eidx,
                        int* __restrict__ deg, int* __restrict__ within,
                        int* __restrict__ degc, int* __restrict__ withinc) {
    int t = blockIdx.x * blockDim.x + threadIdx.x;
    if (t < 131072) {
        // A-frags for rT-GEMM: entry (ut,l,jj) -> w3 element for
        // (u = ut*16 + (l&15), j2 = ((l>>4)&3)*8 + jj), flat r-index u decodes
        // (c,i): c=(f&3)*32+((ll>>4)&3)*8+j0, i=(f>>2)*16+(ll&15).
        int jj = t & 7, l = (t >> 3) & 63, ut = t >> 9;
        int u  = ut*16 + (l & 15);
        int j2 = ((l >> 4) & 3)*8 + jj;
        int f  = u >> 9, ll = (u >> 3) & 63, j0 = u & 7;
        int c  = (f & 3)*32 + ((ll >> 4) & 3)*8 + j0;
        int i  = (f >> 2)*16 + (ll & 15);
        w3t_sw[t] = (__bf16)w3[c*1024 + i*32 + j2];
    } else if (t < 132096) {
        int idx = t - 131072;
        int jj = idx & 7, l = (idx >> 3) & 63, tt = idx >> 9;
        int i  = tt*16 + (l & 15);
        int j2 = ((l >> 4) & 3)*8 + jj;
        b3t_sw[idx] = (__bf16)b3[i*32 + j2];
    } else if (t < 140288) {
        // A-frags for k2T = w2^T @ k1^T: (ct,ks,l,jj) -> w2[ch][c]
        int idx = t - 132096;
        int jj = idx & 7, l = (idx >> 3) & 63, g = idx >> 9;
        int ct = g >> 1, ks = g & 1;
        int c  = ct*16 + (l & 15);
        int ch = ks*32 + ((l >> 4) & 3)*8 + jj;
        w2t_sw[idx] = (__bf16)w2[ch*128 + c];
    } else if (t < 142336) {
        // B-frags for phi MFMA: (ot,l,jj) -> cm_w1[i][o]
        int idx = t - 140288;
        int jj = idx & 7, l = (idx >> 3) & 63, ot = idx >> 9;
        int o  = ot*16 + (l & 15);
        int i  = ((l >> 4) & 3)*8 + jj;
        cmw1_sw[idx] = (__bf16)cw1[i*32 + o];
    } else if (t < 142336 + NN) {
        int n = t - 142336;
        float x0 = x[n*3+0], x1 = x[n*3+1], x2 = x[n*3+2];
        #pragma unroll
        for (int j = 0; j < 32; j += 4) {
            f32x4 a = *(const f32x4*)(fc1b + j);
            a += x0 * (*(const f32x4*)(fc1w + 0*32 + j));
            a += x1 * (*(const f32x4*)(fc1w + 1*32 + j));
            a += x2 * (*(const f32x4*)(fc1w + 2*32 + j));
            *(f32x4*)(h + n*32 + j) = a;   // no relu on fc1 (matches reference)
        }
        coord[n*3+0] = cinit[n*3+0];
        coord[n*3+1] = cinit[n*3+1];
        coord[n*3+2] = cinit[n*3+2];
    } else if (t < 142336 + NN + NE) {
        int e = t - 142336 - NN;
        within[e] = atomicAdd(&deg[eidx[e]], 1);
    } else if (t < 142336 + NN + 2*NE) {
        int e = t - 142336 - NN - NE;
        withinc[e] = atomicAdd(&degc[eidx[NE + e]], 1);
    }
}

// One fused barrier ladder computing all three exclusive scans at once:
// row CSR (deg), col CSR (degc), segment scan+fill. 1 block x 1024 threads.
__global__ __launch_bounds__(1024, 1)
void k_scan(const int* __restrict__ deg, int* __restrict__ rowptr,
            float* __restrict__ deg_inv,
            const int* __restrict__ degc, int* __restrict__ colptr,
            int* __restrict__ seg_meta, int* __restrict__ seg_start) {
    __shared__ int s0a[1024], s1a[1024], s2a[1024];
    const int tid = threadIdx.x;
    const int CH = 10;                       // 1024*10 >= 10000
    const int base = tid * CH;

    int a = 0, b = 0, c = 0;
    for (int i = 0; i < CH; ++i) {
        int n = base + i;
        if (n < NN) {
            int d0 = deg[n], d1 = degc[n];
            a += d0; b += d1; c += (d1 + 15) >> 4;
        }
    }
    s0a[tid] = a; s1a[tid] = b; s2a[tid] = c;
    __syncthreads();
    for (int off = 1; off < 1024; off <<= 1) {
        int t0 = (tid >= off) ? s0a[tid - off] : 0;
        int t1 = (tid >= off) ? s1a[tid - off] : 0;
        int t2 = (tid >= off) ? s2a[tid - off] : 0;
        __syncthreads();
        s0a[tid] += t0; s1a[tid] += t1; s2a[tid] += t2;
        __syncthreads();
    }
    int run0 = s0a[tid] - a;
    int run1 = s1a[tid] - b;
    int run2 = s2a[tid] - c;
    for (int i = 0; i < CH; ++i) {
        int n = base + i;
        if (n < NN) {
            int d0 = deg[n];
            rowptr[n] = run0; run0 += d0;
            deg_inv[n] = 1.0f / (float)(d0 > 1 ? d0 : 1);
            int d1 = degc[n];
            colptr[n] = run1;
            int ns = (d1 + 15) >> 4;
            for (int k = 0; k < ns; ++k) {
                int cnt = d1 - k*16; if (cnt > 16) cnt = 16;
                seg_meta[run2 + k]  = n | (cnt << 16);
                seg_start[run2 + k] = run1 + k*16;
            }
            run1 += d1; run2 += ns;
        }
    }
    if (tid == 1023) { rowptr[NN] = s0a[1023]; colptr[NN] = s1a[1023]; }
    __syncthreads();
    int nseg = s2a[1023];
    for (int sg = nseg + tid; sg < NSEG_MAX; sg += 1024) {
        seg_meta[sg] = -1;
        seg_start[sg] = 0;
    }
}

// After scans: build col-sorted per-edge arrays (pos, row, pre-gathered attrs).
__global__ void k_setup2(const int* __restrict__ eidx, const float* __restrict__ eattr,
                         const int* __restrict__ rowptr, const int* __restrict__ within,
                         const int* __restrict__ colptr, const int* __restrict__ withinc,
                         int* __restrict__ cs_pos, int* __restrict__ cs_row,
                         float* __restrict__ eattr_cs) {
    int e = blockIdx.x * blockDim.x + threadIdx.x;
    if (e >= NE) return;
    int row = eidx[e], col = eidx[NE + e];
    int pos = rowptr[row] + within[e];
    int cs  = colptr[col] + withinc[e];
    cs_pos[cs] = pos; cs_row[cs] = row;
    #pragma unroll
    for (int a = 0; a < 6; ++a) eattr_cs[(size_t)cs*8 + a] = eattr[(size_t)e*6 + a];
    eattr_cs[(size_t)cs*8 + 6] = 0.f; eattr_cs[(size_t)cs*8 + 7] = 0.f;
}

// ---------------- the fused per-layer edge kernel ----------------
// Round-11 winner (k_edge 49.2 us, spill-free: full r in 128 KB LDS, ONE
// barrier, float shfls) + ONE register-pressure-NEGATIVE edit: direct phi
// store from the owning lane (deletes int pr[4] + 4 pos-shuffles).
// Locked lessons: any ADDED register pressure spills at the compiler's
// pinned 64-VGPR allocation (r9/r10/r12); occupancy cannot be raised (r10).
__global__ __launch_bounds__(1024, 4)
void k_edge(const int* __restrict__ seg_meta, const int* __restrict__ seg_start,
            const int* __restrict__ cs_pos, const int* __restrict__ cs_row,
            const float* __restrict__ eattr_cs, const float* __restrict__ coord,
            const float* __restrict__ w1, const float* __restrict__ b1,
            const __bf16* __restrict__ w2t_sw, const float* __restrict__ b2,
            const __bf16* __restrict__ w3t_sw, const __bf16* __restrict__ b3t_sw,
            const float* __restrict__ h,
            const __bf16* __restrict__ cmw1_sw, const float* __restrict__ cm_b1,
            const float* __restrict__ cm_w2,
            float* __restrict__ cds, float* __restrict__ m_s,
            float* __restrict__ phis) {
    __shared__ __align__(16) __bf16 r_lds[16 * 4096];   // 128 KB: FULL r for 16 v
    __shared__ __align__(16) __bf16 wlds[10240];        // 20 KB: w2t + cmw1
    const int tid  = threadIdx.x;
    const int lane = tid & 63;
    const int wave = tid >> 6;                          // 0..15 = segment slot
    const int q  = lane >> 4;
    const int el = lane & 15;
    const int sb = blockIdx.x * 16;
    if (seg_meta[sb] < 0) return;                       // packed: uniform exit

    // stage w2t (16 KB) + cmw1 (4 KB) into LDS
    {
        ((f32x4*)wlds)[tid] = ((const f32x4*)w2t_sw)[tid];
        if (tid < 256) ((f32x4*)(wlds + 8192))[tid] = ((const f32x4*)cmw1_sw)[tid];
    }

    // segment metadata
    const int mown = seg_meta[sb + wave];
    const bool live = mown >= 0;
    const int v_own = live ? (mown & 0xFFFF) : 0;
    const int cnt   = mown >> 16;                       // <0 if dead
    int start = seg_start[sb + wave];

    // B-frag for r-GEMM: col el = h[v_el][q*8 + jj]
    const int mel = seg_meta[sb + el];
    const int vel = (mel < 0) ? 0 : (mel & 0xFFFF);
    bf16x8 bfrag;
    {
        const float* hp = h + (size_t)vel * 32 + q * 8;
        f32x4 h0 = *(const f32x4*)hp;
        f32x4 h1 = *(const f32x4*)(hp + 4);
        bfrag[0]=(__bf16)h0.x; bfrag[1]=(__bf16)h0.y; bfrag[2]=(__bf16)h0.z; bfrag[3]=(__bf16)h0.w;
        bfrag[4]=(__bf16)h1.x; bfrag[5]=(__bf16)h1.y; bfrag[6]=(__bf16)h1.z; bfrag[7]=(__bf16)h1.w;
    }

    // own-edge data (issued early; latency hides under phase A)
    int slot = start + el; if (slot >= NE) slot = NE - 1;
    const int pos   = cs_pos[slot];
    const int rnode = cs_row[slot];
    const float dx = coord[rnode*3+0] - coord[v_own*3+0];
    const float dy = coord[rnode*3+1] - coord[v_own*3+1];
    const float dz = coord[rnode*3+2] - coord[v_own*3+2];
    const float rad = dx*dx + dy*dy + dz*dz;
    f32x4 ea0 = *(const f32x4*)(eattr_cs + (size_t)slot*8);
    f32x4 ea1 = *(const f32x4*)(eattr_cs + (size_t)slot*8 + 4);
    const float kin[7] = {ea0.x, ea0.y, ea0.z, ea0.w, ea1.x, ea1.y, rad};

    const f32x4 zero = {0.f, 0.f, 0.f, 0.f};

    // full r-GEMM: 16 ut-tiles per wave, all 16 v cols, all 8 frag groups.
    // wave w covers idx = w*16..w*16+15 -> (f = idx>>5, g = idx&31), each
    // (f,g) exactly once across the block.
    {
        #pragma unroll
        for (int s = 0; s < 16; ++s) {
            const int idx = wave*16 + s;             // 0..255
            const int f = idx >> 5, g = idx & 31;
            bf16x8 af = *(const bf16x8*)(w3t_sw + ((size_t)(f*32 + g)*64 + lane)*8);
            f32x4 c = __builtin_amdgcn_mfma_f32_16x16x32_bf16(af, bfrag, zero, 0, 0, 0);
            const int wb = el*8192 + ((f*1024 + g*32 + q*8) ^ ((el & 7) << 4));
            *(uint2*)((char*)r_lds + wb) = make_uint2(pk2(c.x, c.y), pk2(c.z, c.w));
        }
    }

    // ---- k1: lane computes channels {ks*32 + q*8 + jj} for its own edge el ----
    bf16x8 k1f[2];
    #pragma unroll
    for (int ks = 0; ks < 2; ++ks) {
        const int c0 = ks*32 + q*8;
        f32x4 a0 = *(const f32x4*)(b1 + c0);
        f32x4 a1 = *(const f32x4*)(b1 + c0 + 4);
        #pragma unroll
        for (int a = 0; a < 7; ++a) {
            const float kv = kin[a];
            a0 += kv * (*(const f32x4*)(w1 + a*64 + c0));
            a1 += kv * (*(const f32x4*)(w1 + a*64 + c0 + 4));
        }
        a0 = relu4(a0); a1 = relu4(a1);
        bf16x8 t;
        t[0]=(__bf16)a0.x; t[1]=(__bf16)a0.y; t[2]=(__bf16)a0.z; t[3]=(__bf16)a0.w;
        t[4]=(__bf16)a1.x; t[5]=(__bf16)a1.y; t[6]=(__bf16)a1.z; t[7]=(__bf16)a1.w;
        k1f[ks] = t;
    }

    __syncthreads();                // the ONLY barrier: wlds + full r ready

    // ---- k2T[c x e]: 8 c-tiles; lane holds (c = ct*16+q*4+r, e = el) ----
    f32x4 C2[8];
    #pragma unroll
    for (int ct = 0; ct < 8; ++ct) {
        f32x4 acc = zero;
        #pragma unroll
        for (int ks = 0; ks < 2; ++ks) {
            bf16x8 af = *(const bf16x8*)(wlds + ((ct*2 + ks)*64 + lane)*8);
            acc = __builtin_amdgcn_mfma_f32_16x16x32_bf16(af, k1f[ks], acc, 0, 0, 0);
        }
        f32x4 bb = *(const f32x4*)(b2 + ct*16 + q*4);
        C2[ct] = relu4(acc + bb);
    }

    // ---- B-frags k2T[c = ks2*32+q*8+jj][e = el] via intra-wave shfl ----
    const int lowq = q & 1, hiq = q >> 1;
    bf16x8 k2f[4];
    #pragma unroll
    for (int ks2 = 0; ks2 < 4; ++ks2) {
        bf16x8 t;
        #pragma unroll
        for (int hh = 0; hh < 2; ++hh) {
            const int src = (lowq*2 + hh)*16 + el;
            #pragma unroll
            for (int rr = 0; rr < 4; ++rr) {
                const float x0 = __shfl(C2[ks2*2][rr],     src, 64);
                const float x1 = __shfl(C2[ks2*2 + 1][rr], src, 64);
                t[hh*4 + rr] = (__bf16)(hiq ? x1 : x0);
            }
        }
        k2f[ks2] = t;
    }

    // ---- m: M[f>>2] += rA[f] x k2f[f&3], f = 0..7 (one rA load at a time) ----
    f32x4 M0 = zero, M1 = zero;
    #pragma unroll
    for (int f = 0; f < 8; ++f) {
        const int rb = wave*8192 + ((f*1024 + lane*16) ^ ((wave & 7) << 4));
        bf16x8 rA = *(const bf16x8*)((const char*)r_lds + rb);
        if (f < 4) M0 = __builtin_amdgcn_mfma_f32_16x16x32_bf16(rA, k2f[f & 3], M0, 0, 0, 0);
        else       M1 = __builtin_amdgcn_mfma_f32_16x16x32_bf16(rA, k2f[f & 3], M1, 0, 0, 0);
    }

    // ---- bt[v][i] via 2 MFMAs + producer-lane shfl (col = wave) ----
    {
        bf16x8 a0 = *(const bf16x8*)(b3t_sw + ((size_t)0*64 + lane)*8);
        bf16x8 a1 = *(const bf16x8*)(b3t_sw + ((size_t)1*64 + lane)*8);
        f32x4 bt0 = __builtin_amdgcn_mfma_f32_16x16x32_bf16(a0, bfrag, zero, 0, 0, 0);
        f32x4 bt1 = __builtin_amdgcn_mfma_f32_16x16x32_bf16(a1, bfrag, zero, 0, 0, 0);
        f32x4 btv0, btv1;
        #pragma unroll
        for (int r = 0; r < 4; ++r) {
            btv0[r] = __shfl(bt0[r], (lane & 48) + wave, 64);
            btv1[r] = __shfl(bt1[r], (lane & 48) + wave, 64);
        }
        M0 += btv0; M1 += btv1;
    }

    const bool ev = live && (el < cnt);
    if (ev) {
        *(f32x4*)(m_s + (size_t)pos*32 + q*4)      = M0;
        *(f32x4*)(m_s + (size_t)pos*32 + 16 + q*4) = M1;
        if (q == 0) {
            f32x4 cdv = {dx, dy, dz, rad};
            *(f32x4*)(cds + (size_t)pos*4) = cdv;
        }
    }

    // ---- phi: A-frag m[e = el][i = q*8+jj] via shfl, then 2 MFMAs ----
    bf16x8 paf;
    #pragma unroll
    for (int hh = 0; hh < 2; ++hh) {
        const int src = (lowq*2 + hh)*16 + el;
        #pragma unroll
        for (int rr = 0; rr < 4; ++rr) {
            const float x0 = __shfl(M0[rr], src, 64);
            const float x1 = __shfl(M1[rr], src, 64);
            paf[hh*4 + rr] = (__bf16)(hiq ? x1 : x0);
        }
    }
    bf16x8 bf0 = *(const bf16x8*)(wlds + 8192 + (0*64 + lane)*8);
    bf16x8 bf1 = *(const bf16x8*)(wlds + 8192 + (1*64 + lane)*8);
    f32x4 PH0 = __builtin_amdgcn_mfma_f32_16x16x32_bf16(paf, bf0, zero, 0, 0, 0);
    f32x4 PH1 = __builtin_amdgcn_mfma_f32_16x16x32_bf16(paf, bf1, zero, 0, 0, 0);

    const float b1v0 = cm_b1[el], b1v1 = cm_b1[16 + el];
    const float w2v0 = cm_w2[el], w2v1 = cm_w2[16 + el];
    float ph[4];
    #pragma unroll
    for (int r = 0; r < 4; ++r) {
        float s0 = fmaxf(PH0[r] + b1v0, 0.f) * w2v0
                 + fmaxf(PH1[r] + b1v1, 0.f) * w2v1;
        s0 += __shfl_xor(s0, 1, 64);
        s0 += __shfl_xor(s0, 2, 64);
        s0 += __shfl_xor(s0, 4, 64);
        s0 += __shfl_xor(s0, 8, 64);
        ph[r] = s0;                      // phi of edge q*4+r, uniform across el
    }
    // direct store: lane (q, el = q*4+r) owns edge el and already holds its pos
    if (live && (el >> 2) == q && el < cnt)
        phis[pos] = ph[el & 3];
}

// CSR gather, 16 threads/node (sub owns channels {2*sub, 2*sub+1} via float2).
__global__ __launch_bounds__(256, 4)
void k_gather(const int* __restrict__ rowptr,
              const float* __restrict__ m_s, const float* __restrict__ phis,
              const float* __restrict__ cds, const float* __restrict__ deg_inv,
              float* __restrict__ coord, float* __restrict__ h,
              const float* __restrict__ fw1, const float* __restrict__ fb1,
              const float* __restrict__ fw2, const float* __restrict__ fb2,
              float* __restrict__ out, int dofinal) {
    int tid = blockIdx.x * blockDim.x + threadIdx.x;
    int n = tid >> 4, sub = tid & 15;
    if (n >= NN) return;
    int st = rowptr[n], en = rowptr[n+1];
    f32x2 am0 = {0.f, 0.f}, am1 = {0.f, 0.f};
    f32x2 am2 = {0.f, 0.f}, am3 = {0.f, 0.f};
    int p = st;
    for (; p + 3 < en; p += 4) {
        am0 += *(const f32x2*)(m_s + (size_t)p*32 + sub*2);
        am1 += *(const f32x2*)(m_s + (size_t)(p+1)*32 + sub*2);
        am2 += *(const f32x2*)(m_s + (size_t)(p+2)*32 + sub*2);
        am3 += *(const f32x2*)(m_s + (size_t)(p+3)*32 + sub*2);
    }
    for (; p < en; ++p)
        am0 += *(const f32x2*)(m_s + (size_t)p*32 + sub*2);
    f32x2 am = (am0 + am1) + (am2 + am3);

    float di = deg_inv[n];
    f32x2 hv = *(const f32x2*)(h + (size_t)n*32 + sub*2);
    hv.x = fmaxf(hv.x + am.x * di, 0.f);
    hv.y = fmaxf(hv.y + am.y * di, 0.f);

    // phi*cd: each sub handles edges st+sub, st+sub+16, ...; 4-level reduce
    float cx = 0.f, cy = 0.f, cz = 0.f;
    for (int pp = st + sub; pp < en; pp += 16) {
        f32x4 cd = *(const f32x4*)(cds + (size_t)pp*4);
        float ph = phis[pp];
        cx += cd.x * ph; cy += cd.y * ph; cz += cd.z * ph;
    }
    cx += __shfl_xor(cx, 1, 64); cy += __shfl_xor(cy, 1, 64); cz += __shfl_xor(cz, 1, 64);
    cx += __shfl_xor(cx, 2, 64); cy += __shfl_xor(cy, 2, 64); cz += __shfl_xor(cz, 2, 64);
    cx += __shfl_xor(cx, 4, 64); cy += __shfl_xor(cy, 4, 64); cz += __shfl_xor(cz, 4, 64);
    cx += __shfl_xor(cx, 8, 64); cy += __shfl_xor(cy, 8, 64); cz += __shfl_xor(cz, 8, 64);
    float c0 = 0.f, c1 = 0.f, c2 = 0.f;
    if (sub == 0) {
        c0 = coord[n*3+0] + cx * di;
        c1 = coord[n*3+1] + cy * di;
        c2 = coord[n*3+2] + cz * di;
    }

    if (!dofinal) {
        *(f32x2*)(h + (size_t)n*32 + sub*2) = hv;
        if (sub == 0) {
            coord[n*3+0] = c0; coord[n*3+1] = c1; coord[n*3+2] = c2;
        }
        return;
    }

    // fused final MLP: node group = 16 lanes; collect h[0..31] via shfl
    const int gbase = (tid & 63) & 48;
    float hreg[32];
    #pragma unroll
    for (int i = 0; i < 16; ++i) {
        hreg[i*2+0] = __shfl(hv.x, gbase + i, 64);
        hreg[i*2+1] = __shfl(hv.y, gbase + i, 64);
    }
    float po;
    {
        const int o = sub*4;
        f32x4 a = *(const f32x4*)(fb1 + o);
        #pragma unroll
        for (int i = 0; i < 32; ++i)
            a += hreg[i] * (*(const f32x4*)(fw1 + i*64 + o));
        a = relu4(a);
        f32x4 w2 = *(const f32x4*)(fw2 + o);
        po = a.x*w2.x + a.y*w2.y + a.z*w2.z + a.w*w2.w;
    }
    po += __shfl_xor(po, 1, 64);
    po += __shfl_xor(po, 2, 64);
    po += __shfl_xor(po, 4, 64);
    po += __shfl_xor(po, 8, 64);
    if (sub == 0) {
        out[n] = po + fb2[0];
        out[NN + n*3 + 0] = c0;
        out[NN + n*3 + 1] = c1;
        out[NN + n*3 + 2] = c2;
    }
}

// ---------------- launch ----------------

extern "C" void kernel_launch(void* const* d_in, const int* in_sizes, int n_in,
                              void* d_out, int out_size, void* d_ws, size_t ws_size,
                              hipStream_t stream) {
    const float* x      = (const float*)d_in[0];
    const int*   eidx   = (const int*)  d_in[1];
    const float* eattr  = (const float*)d_in[2];
    const float* cinit  = (const float*)d_in[3];
    const float* fc1w   = (const float*)d_in[4];
    const float* fc1b   = (const float*)d_in[5];
    const float* kw1    = (const float*)d_in[6];
    const float* kb1    = (const float*)d_in[7];
    const float* kw2    = (const float*)d_in[8];
    const float* kb2    = (const float*)d_in[9];
    const float* kw3    = (const float*)d_in[10];
    const float* kb3    = (const float*)d_in[11];
    const float* cmw1   = (const float*)d_in[12];
    const float* cmb1   = (const float*)d_in[13];
    const float* cmw2   = (const float*)d_in[14];
    const float* f2w1   = (const float*)d_in[15];
    const float* f2b1   = (const float*)d_in[16];
    const float* f2w2   = (const float*)d_in[17];
    const float* f2b2   = (const float*)d_in[18];
    float* out = (float*)d_out;

    char* p = (char*)d_ws;
    auto carve = [&](size_t bytes) {
        void* r = (void*)p;
        p += (bytes + 255) & ~(size_t)255;
        return r;
    };
    float*  h        = (float*) carve((size_t)NN * 32 * 4);
    float*  coord    = (float*) carve((size_t)NN * 3 * 4);
    int*    deg      = (int*)   carve((size_t)NN * 4);     // deg+degc adjacent:
    int*    degc     = (int*)   carve((size_t)NN * 4);     // ONE merged memset
    float*  deg_inv  = (float*) carve((size_t)NN * 4);
    int*    rowptr   = (int*)   carve((size_t)(NN + 1) * 4);
    int*    within   = (int*)   carve((size_t)NE * 4);
    int*    colptr   = (int*)   carve((size_t)(NN + 1) * 4);
    int*    withinc  = (int*)   carve((size_t)NE * 4);
    int*    cs_pos   = (int*)   carve((size_t)NE * 4);
    int*    cs_row   = (int*)   carve((size_t)NE * 4);
    float*  eattr_cs = (float*) carve((size_t)NE * 8 * 4);
    int*    seg_meta = (int*)   carve((size_t)NSEG_MAX * 4);
    int*    seg_start= (int*)   carve((size_t)NSEG_MAX * 4);
    float*  cds      = (float*) carve((size_t)NE * 4 * 4);
    float*  m_s      = (float*) carve((size_t)NE * 32 * 4);
    float*  phis     = (float*) carve((size_t)NE * 4);
    __bf16* w3t_sw   = (__bf16*)carve((size_t)131072 * 2);
    __bf16* b3t_sw   = (__bf16*)carve((size_t)1024 * 2);
    __bf16* w2t_sw   = (__bf16*)carve((size_t)8192 * 2);
    __bf16* cmw1_sw  = (__bf16*)carve((size_t)2048 * 2);

    const int TB = 256;
    dim3 b(TB);
    const int totS = 142336 + NN + 2*NE;
    dim3 gS((totS + TB - 1) / TB);
    dim3 gS2((NE + TB - 1) / TB);
    dim3 gE(NSEG_MAX / 16);       // 16 segments per 1024-thread block
    dim3 gA((NN*16 + TB - 1) / TB);

    // single memset covers deg + pad + degc (pad zeroing is harmless)
    hipMemsetAsync(deg, 0, (size_t)((char*)degc - (char*)deg) + (size_t)NN * 4, stream);
    k_setup<<<gS, b, 0, stream>>>(kw3, w3t_sw, kb3, b3t_sw, kw2, w2t_sw, cmw1, cmw1_sw,
                                  x, fc1w, fc1b, cinit, h, coord, eidx,
                                  deg, within, degc, withinc);
    k_scan<<<1, dim3(1024), 0, stream>>>(deg, rowptr, deg_inv, degc, colptr,
                                         seg_meta, seg_start);
    k_setup2<<<gS2, b, 0, stream>>>(eidx, eattr, rowptr, within, colptr, withinc,
                                    cs_pos, cs_row, eattr_cs);

    for (int d = 0; d < 3; ++d) {
        k_edge<<<gE, dim3(1024), 0, stream>>>(seg_meta, seg_start, cs_pos, cs_row,
                                              eattr_cs, coord, kw1, kb1, w2t_sw, kb2,
                                              w3t_sw, b3t_sw, h, cmw1_sw, cmb1, cmw2,
                                              cds, m_s, phis);
        k_gather<<<gA, b, 0, stream>>>(rowptr, m_s, phis, cds, deg_inv, coord, h,
                                       f2w1, f2b1, f2w2, f2b2, out, d == 2 ? 1 : 0);
    }
}